// Round 1
// baseline (404.285 us; speedup 1.0000x reference)
//
#include <hip/hip_runtime.h>

typedef __bf16 bf16;
typedef bf16 bf16x8 __attribute__((ext_vector_type(8)));
typedef float f32x4 __attribute__((ext_vector_type(4)));
typedef unsigned int u32;
typedef unsigned short u16;

#define BB 4
#define SS 4096
#define DD 1024
#define EE 64
static constexpr float SCALE2 = 0.18033688011112042f; // (1/8)*log2(e)

#define MFMA(a,b,c) __builtin_amdgcn_mfma_f32_16x16x32_bf16((a),(b),(c),0,0,0)

typedef __attribute__((address_space(3))) unsigned int lds_u32;
typedef const __attribute__((address_space(1))) unsigned int glb_u32;

static __device__ __forceinline__ void gload16(const void* g, void* l) {
    __builtin_amdgcn_global_load_lds((glb_u32*)g, (lds_u32*)l, 16, 0, 0);
}

static __device__ __forceinline__ u16 f2bf(float x) {
    union { float f; u32 u; } v; v.f = x;
    u32 r = v.u + 0x7FFFu + ((v.u >> 16) & 1u);
    return (u16)(r >> 16);
}
static __device__ __forceinline__ u32 pk2(float a, float b) {
    return (u32)f2bf(a) | ((u32)f2bf(b) << 16);
}
static __device__ __forceinline__ float fexp2(float x) {
    return __builtin_amdgcn_exp2f(x);
}

// ---------------- Kernel 1: Q/K projection GEMM (fp32 in -> bf16 out) ----------------
__global__ __launch_bounds__(512, 4) void k_proj(const float* __restrict__ enc,
                                                 const float* __restrict__ wq,
                                                 const float* __restrict__ wk,
                                                 u16* __restrict__ qout,
                                                 u16* __restrict__ kout) {
    __shared__ __align__(16) u16 la[128 * 72];
    __shared__ __align__(16) u16 lw[128 * 72];
    const int tid = threadIdx.x;
    const int m0 = blockIdx.x * 128;
    const int row = tid >> 2;
    const int c0 = (tid & 3) << 4;
    const int w = tid >> 6, lane = tid & 63, l15 = lane & 15, quad = lane >> 4;

    f32x4 acc[8];
#pragma unroll
    for (int i = 0; i < 8; i++) acc[i] = f32x4{0.f, 0.f, 0.f, 0.f};

    const float* arow = enc + (size_t)(m0 + row) * DD;
    const float* wrow = (row < 64) ? (wq + (size_t)row * DD) : (wk + (size_t)(row - 64) * DD);

    for (int kk = 0; kk < DD; kk += 64) {
        __syncthreads();
        float4 a0 = *(const float4*)(arow + kk + c0);
        float4 a1 = *(const float4*)(arow + kk + c0 + 4);
        float4 a2 = *(const float4*)(arow + kk + c0 + 8);
        float4 a3 = *(const float4*)(arow + kk + c0 + 12);
        float4 b0 = *(const float4*)(wrow + kk + c0);
        float4 b1 = *(const float4*)(wrow + kk + c0 + 4);
        float4 b2 = *(const float4*)(wrow + kk + c0 + 8);
        float4 b3 = *(const float4*)(wrow + kk + c0 + 12);
        uint4 pa0, pa1, pb0, pb1;
        pa0.x = pk2(a0.x, a0.y); pa0.y = pk2(a0.z, a0.w);
        pa0.z = pk2(a1.x, a1.y); pa0.w = pk2(a1.z, a1.w);
        pa1.x = pk2(a2.x, a2.y); pa1.y = pk2(a2.z, a2.w);
        pa1.z = pk2(a3.x, a3.y); pa1.w = pk2(a3.z, a3.w);
        pb0.x = pk2(b0.x, b0.y); pb0.y = pk2(b0.z, b0.w);
        pb0.z = pk2(b1.x, b1.y); pb0.w = pk2(b1.z, b1.w);
        pb1.x = pk2(b2.x, b2.y); pb1.y = pk2(b2.z, b2.w);
        pb1.z = pk2(b3.x, b3.y); pb1.w = pk2(b3.z, b3.w);
        *(uint4*)&la[row * 72 + c0] = pa0;
        *(uint4*)&la[row * 72 + c0 + 8] = pa1;
        *(uint4*)&lw[row * 72 + c0] = pb0;
        *(uint4*)&lw[row * 72 + c0 + 8] = pb1;
        __syncthreads();
#pragma unroll
        for (int es = 0; es < 2; es++) {
            bf16x8 af = *(const bf16x8*)&la[(16 * w + l15) * 72 + es * 32 + quad * 8];
#pragma unroll
            for (int ct = 0; ct < 8; ct++) {
                bf16x8 bf_ = *(const bf16x8*)&lw[(16 * ct + l15) * 72 + es * 32 + quad * 8];
                acc[ct] = MFMA(af, bf_, acc[ct]);
            }
        }
    }
#pragma unroll
    for (int ct = 0; ct < 8; ct++) {
        int n = 16 * ct + l15;
        u16* dst = (ct < 4) ? qout : kout;
        int col = (ct < 4) ? n : (n - 64);
#pragma unroll
        for (int r = 0; r < 4; r++) {
            int grow = m0 + 16 * w + quad * 4 + r;
            dst[(size_t)grow * EE + col] = f2bf(acc[ct][r]);
        }
    }
}

// ---------------- Kernel 2: transpose-cast enc -> Vt[b][d][s] bf16 ----------------
__global__ __launch_bounds__(256) void k_tcast(const float* __restrict__ enc, u16* __restrict__ vt) {
    __shared__ __align__(16) u16 lt[64 * 72];
    const int tid = threadIdx.x;
    const int dt = blockIdx.x, st = blockIdx.y, b = blockIdx.z;
    const int srow = tid >> 2;
    const int d0 = (tid & 3) << 4;
    const float* src = enc + ((size_t)(b * SS + st * 64 + srow) * DD) + dt * 64 + d0;
    float4 f0 = ((const float4*)src)[0];
    float4 f1 = ((const float4*)src)[1];
    float4 f2 = ((const float4*)src)[2];
    float4 f3 = ((const float4*)src)[3];
    float v[16];
    v[0] = f0.x; v[1] = f0.y; v[2] = f0.z; v[3] = f0.w;
    v[4] = f1.x; v[5] = f1.y; v[6] = f1.z; v[7] = f1.w;
    v[8] = f2.x; v[9] = f2.y; v[10] = f2.z; v[11] = f2.w;
    v[12] = f3.x; v[13] = f3.y; v[14] = f3.z; v[15] = f3.w;
#pragma unroll
    for (int j = 0; j < 16; j++) lt[(d0 + j) * 72 + srow] = f2bf(v[j]);
    __syncthreads();
    const int drow = tid >> 2;
    const int s0 = (tid & 3) << 4;
    uint4 r0 = *(const uint4*)&lt[drow * 72 + s0];
    uint4 r1 = *(const uint4*)&lt[drow * 72 + s0 + 8];
    u16* dst = vt + ((size_t)(b * DD + dt * 64 + drow) * SS) + st * 64 + s0;
    *(uint4*)dst = r0;
    *(uint4*)(dst + 8) = r1;
}

// ---------------- Kernel 3: per-row softmax stats (m in log2 units, 1/l) ----------------
__global__ __launch_bounds__(512, 4) void k_stats(const u16* __restrict__ qg, const u16* __restrict__ kg,
                                                  float* __restrict__ mmo, float* __restrict__ lio) {
    __shared__ __align__(16) u16 lq[128 * 64];
    __shared__ __align__(16) u16 lk[64 * 64];
    const int tid = threadIdx.x;
    const int w = tid >> 6, lane = tid & 63, l15 = lane & 15, quad = lane >> 4;
    const int qt = blockIdx.x, b = blockIdx.y;
    const int q0 = qt * 128;
    const u16* qbase = qg + ((size_t)b * SS + q0) * EE;
    const u16* kbase = kg + (size_t)b * SS * EE;
#pragma unroll
    for (int i = 0; i < 2; i++) {
        int goff = w * 128 + i * 64 + lane;
        int grow = goff >> 3, gp = goff & 7, glog = gp ^ (grow & 7);
        gload16(qbase + (size_t)grow * EE + glog * 8, (void*)&lq[(w * 128 + i * 64) * 8]);
    }
    __syncthreads();
    bf16x8 qf[2];
    {
        int n = 16 * w + l15;
#pragma unroll
        for (int es = 0; es < 2; es++) {
            int phys = (es * 4 + quad) ^ (n & 7);
            qf[es] = *(const bf16x8*)&lq[n * 64 + phys * 8];
        }
    }
    float mrun = -3.0e38f, lrun = 0.0f;
    const int KT = 2 * qt + 2;
    for (int kt = 0; kt < KT; kt++) {
        const int k0 = kt * 64;
        __syncthreads();
        {
            int goff = w * 64 + lane;
            int grow = goff >> 3, gp = goff & 7, glog = gp ^ (grow & 7);
            gload16(kbase + (size_t)(k0 + grow) * EE + glog * 8, (void*)&lk[(w * 64) * 8]);
        }
        __syncthreads();
        float tv[16];
        const bool diag = (k0 + 63 > q0 + 16 * w);
#pragma unroll
        for (int rt = 0; rt < 4; rt++) {
            int m = 16 * rt + l15;
            f32x4 c = f32x4{0.f, 0.f, 0.f, 0.f};
#pragma unroll
            for (int es = 0; es < 2; es++) {
                int phys = (es * 4 + quad) ^ (m & 7);
                bf16x8 ka = *(const bf16x8*)&lk[m * 64 + phys * 8];
                c = MFMA(ka, qf[es], c);
            }
#pragma unroll
            for (int r = 0; r < 4; r++) {
                float t = c[r] * SCALE2;
                if (diag) {
                    int kpg = k0 + 16 * rt + 4 * quad + r;
                    int qg_ = q0 + 16 * w + l15;
                    if (kpg > qg_) t = -3.0e38f;
                }
                tv[rt * 4 + r] = t;
            }
        }
        float vm = tv[0];
#pragma unroll
        for (int i = 1; i < 16; i++) vm = fmaxf(vm, tv[i]);
        vm = fmaxf(vm, __shfl_xor(vm, 16, 64));
        vm = fmaxf(vm, __shfl_xor(vm, 32, 64));
        float mnew = fmaxf(mrun, vm);
        float sum = 0.0f;
#pragma unroll
        for (int i = 0; i < 16; i++) sum += fexp2(tv[i] - mnew);
        sum += __shfl_xor(sum, 16, 64);
        sum += __shfl_xor(sum, 32, 64);
        lrun = lrun * fexp2(mrun - mnew) + sum;
        mrun = mnew;
    }
    if (quad == 0) {
        int q = q0 + 16 * w + l15;
        mmo[(size_t)b * SS + q] = mrun;
        lio[(size_t)b * SS + q] = 1.0f / lrun;
    }
}

// ---------------- Kernel 4: fused attention (recompute S^T, exp, PV MFMA) ----------------
__global__ __launch_bounds__(512, 4) void k_attn(const u16* __restrict__ qg, const u16* __restrict__ kg,
                                                 const u16* __restrict__ vt, const float* __restrict__ mmi,
                                                 const float* __restrict__ lii, float* __restrict__ out) {
    __shared__ __align__(16) u16 lq[128 * 64];   // Q tile, XOR-swizzled granules
    __shared__ __align__(16) u16 lk[64 * 64];    // K tile, swizzled
    __shared__ __align__(16) u16 lv[128 * 64];   // Vt tile (row=d, col=k), swizzled
    __shared__ __align__(16) u16 lp[128 * 72];   // P (row=q, stride 72 pad)
    __shared__ float lli[128];
    const int tid = threadIdx.x;
    const int w = tid >> 6, lane = tid & 63, l15 = lane & 15, quad = lane >> 4;
    const int ds = blockIdx.x, qt = blockIdx.y, b = blockIdx.z;
    const int q0 = qt * 128, d0 = ds * 128;
    const int kr = w & 3, qc = w >> 2;   // S^T phase split
    const int dc = w & 3, qr = w >> 2;   // PV phase split
    const u16* qbase = qg + ((size_t)b * SS + q0) * EE;
    const u16* kbase = kg + (size_t)b * SS * EE;
    const u16* vbase = vt + ((size_t)b * DD + d0) * SS;

#pragma unroll
    for (int i = 0; i < 2; i++) {
        int goff = w * 128 + i * 64 + lane;
        int grow = goff >> 3, gp = goff & 7, glog = gp ^ (grow & 7);
        gload16(qbase + (size_t)grow * EE + glog * 8, (void*)&lq[(w * 128 + i * 64) * 8]);
    }
    if (tid < 128) lli[tid] = lii[(size_t)b * SS + q0 + tid];
    __syncthreads();

    bf16x8 qf[4][2];
    float mmv[4];
#pragma unroll
    for (int ct = 0; ct < 4; ct++) {
        int n = 64 * qc + 16 * ct + l15;
#pragma unroll
        for (int es = 0; es < 2; es++) {
            int phys = (es * 4 + quad) ^ (n & 7);
            qf[ct][es] = *(const bf16x8*)&lq[n * 64 + phys * 8];
        }
        mmv[ct] = mmi[(size_t)b * SS + q0 + n];
    }
    f32x4 o[4][2];
#pragma unroll
    for (int i = 0; i < 4; i++)
#pragma unroll
        for (int j = 0; j < 2; j++) o[i][j] = f32x4{0.f, 0.f, 0.f, 0.f};

    const int KT = 2 * qt + 2;
    for (int kt = 0; kt < KT; kt++) {
        const int k0 = kt * 64;
        __syncthreads();   // B0: previous PV done reading lv/lp
        {
            int goff = w * 64 + lane;
            int grow = goff >> 3, gp = goff & 7, glog = gp ^ (grow & 7);
            gload16(kbase + (size_t)(k0 + grow) * EE + glog * 8, (void*)&lk[(w * 64) * 8]);
        }
#pragma unroll
        for (int i = 0; i < 2; i++) {
            int goff = w * 128 + i * 64 + lane;
            int grow = goff >> 3, gp = goff & 7, glog = gp ^ (grow & 7);
            gload16(vbase + (size_t)grow * SS + k0 + glog * 8, (void*)&lv[(w * 128 + i * 64) * 8]);
        }
        __syncthreads();   // B1: K/Vt staged (vmcnt drained by barrier)
        bf16x8 ka[2];
        {
            int m = 16 * kr + l15;
#pragma unroll
            for (int es = 0; es < 2; es++) {
                int phys = (es * 4 + quad) ^ (m & 7);
                ka[es] = *(const bf16x8*)&lk[m * 64 + phys * 8];
            }
        }
        const bool diag = (k0 + 63 > q0);
#pragma unroll
        for (int ct = 0; ct < 4; ct++) {
            f32x4 c = f32x4{0.f, 0.f, 0.f, 0.f};
            c = MFMA(ka[0], qf[ct][0], c);
            c = MFMA(ka[1], qf[ct][1], c);
            int qv = 64 * qc + 16 * ct + l15;
            float p[4];
#pragma unroll
            for (int r = 0; r < 4; r++) {
                float arg = __builtin_fmaf(c[r], SCALE2, -mmv[ct]);
                if (diag) {
                    int kpg = k0 + 16 * kr + 4 * quad + r;
                    if (kpg > q0 + qv) arg = -3.0e38f;
                }
                p[r] = fexp2(arg);
            }
            uint2 pkk;
            pkk.x = pk2(p[0], p[1]);
            pkk.y = pk2(p[2], p[3]);
            *(uint2*)&lp[qv * 72 + 16 * kr + 4 * quad] = pkk;
        }
        __syncthreads();   // B2: P ready
#pragma unroll
        for (int ks = 0; ks < 2; ks++) {
            bf16x8 pa[4];
#pragma unroll
            for (int rt = 0; rt < 4; rt++) {
                int m = 64 * qr + 16 * rt + l15;
                pa[rt] = *(const bf16x8*)&lp[m * 72 + ks * 32 + quad * 8];
            }
#pragma unroll
            for (int ct = 0; ct < 2; ct++) {
                int n = 32 * dc + 16 * ct + l15;
                int phys = (ks * 4 + quad) ^ (n & 7);
                bf16x8 vb = *(const bf16x8*)&lv[n * 64 + phys * 8];
#pragma unroll
                for (int rt = 0; rt < 4; rt++) o[rt][ct] = MFMA(pa[rt], vb, o[rt][ct]);
            }
        }
    }
#pragma unroll
    for (int rt = 0; rt < 4; rt++) {
#pragma unroll
        for (int r = 0; r < 4; r++) {
            int row = 64 * qr + 16 * rt + 4 * quad + r;
            float li = lli[row];
#pragma unroll
            for (int ct = 0; ct < 2; ct++) {
                int col = d0 + 32 * dc + 16 * ct + l15;
                out[((size_t)b * SS + q0 + row) * DD + col] = o[rt][ct][r] * li;
            }
        }
    }
}

extern "C" void kernel_launch(void* const* d_in, const int* in_sizes, int n_in,
                              void* d_out, int out_size, void* d_ws, size_t ws_size,
                              hipStream_t stream) {
    (void)in_sizes; (void)n_in; (void)out_size; (void)ws_size;
    const float* enc = (const float*)d_in[0];
    const float* wq = (const float*)d_in[1];
    const float* wk = (const float*)d_in[2];
    char* ws = (char*)d_ws;
    u16* qbf = (u16*)ws;                                   // 2 MiB
    u16* kbf = (u16*)(ws + (2ull << 20));                  // 2 MiB
    u16* vt  = (u16*)(ws + (4ull << 20));                  // 32 MiB
    float* mm = (float*)(ws + (36ull << 20));              // 64 KiB
    float* li = (float*)(ws + (36ull << 20) + SS * BB * 4);// 64 KiB
    float* out = (float*)d_out;

    hipLaunchKernelGGL(k_proj, dim3(128), dim3(512), 0, stream, enc, wq, wk, qbf, kbf);
    hipLaunchKernelGGL(k_tcast, dim3(16, 64, 4), dim3(256), 0, stream, enc, vt);
    hipLaunchKernelGGL(k_stats, dim3(32, 4), dim3(512), 0, stream, qbf, kbf, mm, li);
    hipLaunchKernelGGL(k_attn, dim3(8, 32, 4), dim3(512), 0, stream, qbf, kbf, vt, mm, li, out);
}

// Round 2
// 397.903 us; speedup vs baseline: 1.0160x; 1.0160x over previous
//
#include <hip/hip_runtime.h>

typedef __bf16 bf16;
typedef bf16 bf16x8 __attribute__((ext_vector_type(8)));
typedef float f32x4 __attribute__((ext_vector_type(4)));
typedef unsigned int u32;
typedef unsigned short u16;

#define BB 4
#define SS 4096
#define DD 1024
#define EE 64
static constexpr float SCALE2 = 0.18033688011112042f; // (1/8)*log2(e)
static constexpr float MFIX = 16.0f;                  // fixed softmax shift (log2 domain)

#define MFMA(a,b,c) __builtin_amdgcn_mfma_f32_16x16x32_bf16((a),(b),(c),0,0,0)

typedef __attribute__((address_space(3))) unsigned int lds_u32;
typedef const __attribute__((address_space(1))) unsigned int glb_u32;

static __device__ __forceinline__ void gload16(const void* g, void* l) {
    __builtin_amdgcn_global_load_lds((glb_u32*)g, (lds_u32*)l, 16, 0, 0);
}

static __device__ __forceinline__ u16 f2bf(float x) {
    union { float f; u32 u; } v; v.f = x;
    u32 r = v.u + 0x7FFFu + ((v.u >> 16) & 1u);
    return (u16)(r >> 16);
}
static __device__ __forceinline__ u32 pk2(float a, float b) {
    return (u32)f2bf(a) | ((u32)f2bf(b) << 16);
}
static __device__ __forceinline__ float fexp2(float x) {
    return __builtin_amdgcn_exp2f(x);
}

// ---------------- Kernel 1: Q/K projection GEMM (fp32 in -> bf16 out) ----------------
// 256 blocks: blockIdx.x = {m-tile(128 rows) x 2 halves (Q|K)}; swizzled LDS, no pad.
__global__ __launch_bounds__(512, 4) void k_proj(const float* __restrict__ enc,
                                                 const float* __restrict__ wq,
                                                 const float* __restrict__ wk,
                                                 u16* __restrict__ qout,
                                                 u16* __restrict__ kout) {
    __shared__ __align__(16) u16 la[128 * 64];
    __shared__ __align__(16) u16 lw[64 * 64];
    const int tid = threadIdx.x;
    const int half = blockIdx.x & 1;
    const int m0 = (blockIdx.x >> 1) * 128;
    const int w = tid >> 6, lane = tid & 63, l15 = lane & 15, quad = lane >> 4;
    const int ari = tid >> 2, ac0 = (tid & 3) << 4;   // A staging: 128 rows x 16 floats
    const int wri = tid >> 3, wc0 = (tid & 7) << 3;   // W staging: 64 rows x 8 floats
    const float* arow = enc + (size_t)(m0 + ari) * DD + ac0;
    const float* wbase = half ? wk : wq;
    const float* wrow = wbase + (size_t)wri * DD + wc0;
    u16* dst = half ? kout : qout;

    f32x4 acc[4];
#pragma unroll
    for (int i = 0; i < 4; i++) acc[i] = f32x4{0.f, 0.f, 0.f, 0.f};

    for (int kk = 0; kk < DD; kk += 64) {
        __syncthreads();
        float4 a0 = *(const float4*)(arow + kk);
        float4 a1 = *(const float4*)(arow + kk + 4);
        float4 a2 = *(const float4*)(arow + kk + 8);
        float4 a3 = *(const float4*)(arow + kk + 12);
        float4 b0 = *(const float4*)(wrow + kk);
        float4 b1 = *(const float4*)(wrow + kk + 4);
        uint4 pa0, pa1, pw;
        pa0.x = pk2(a0.x, a0.y); pa0.y = pk2(a0.z, a0.w);
        pa0.z = pk2(a1.x, a1.y); pa0.w = pk2(a1.z, a1.w);
        pa1.x = pk2(a2.x, a2.y); pa1.y = pk2(a2.z, a2.w);
        pa1.z = pk2(a3.x, a3.y); pa1.w = pk2(a3.z, a3.w);
        pw.x = pk2(b0.x, b0.y); pw.y = pk2(b0.z, b0.w);
        pw.z = pk2(b1.x, b1.y); pw.w = pk2(b1.z, b1.w);
        int ag = ac0 >> 3;  // logical 16B-granule (2 per thread)
        int ap0 = (ag + 0) ^ (ari & 7);
        int ap1 = (ag + 1) ^ (ari & 7);
        *(uint4*)&la[ari * 64 + ap0 * 8] = pa0;
        *(uint4*)&la[ari * 64 + ap1 * 8] = pa1;
        int wp = (wc0 >> 3) ^ (wri & 7);
        *(uint4*)&lw[wri * 64 + wp * 8] = pw;
        __syncthreads();
        int m = 16 * w + l15;
#pragma unroll
        for (int es = 0; es < 2; es++) {
            bf16x8 af = *(const bf16x8*)&la[m * 64 + ((((es << 2) + quad) ^ (m & 7))) * 8];
#pragma unroll
            for (int ct = 0; ct < 4; ct++) {
                int n = 16 * ct + l15;
                bf16x8 bf_ = *(const bf16x8*)&lw[n * 64 + ((((es << 2) + quad) ^ (n & 7))) * 8];
                acc[ct] = MFMA(af, bf_, acc[ct]);
            }
        }
    }
#pragma unroll
    for (int ct = 0; ct < 4; ct++) {
        int col = 16 * ct + l15;
#pragma unroll
        for (int r = 0; r < 4; r++) {
            int grow = m0 + 16 * w + 4 * quad + r;
            dst[(size_t)grow * EE + col] = f2bf(acc[ct][r]);
        }
    }
}

// ---------------- Kernel 2: transpose-cast enc -> Vt[b][d][s] bf16 (conflict-free) ----
__global__ __launch_bounds__(256) void k_tcast(const float* __restrict__ enc, u16* __restrict__ vt) {
    __shared__ u32 lt2[32][67];   // row = d-pair, col = s; stride 67 => <=2-way banks
    const int tid = threadIdx.x;
    const int dt = blockIdx.x, st = blockIdx.y, b = blockIdx.z;
    const int srow = tid >> 2, d0 = (tid & 3) << 4;
    const float* src = enc + ((size_t)(b * SS + st * 64 + srow) * DD) + dt * 64 + d0;
    float4 f0 = ((const float4*)src)[0];
    float4 f1 = ((const float4*)src)[1];
    float4 f2 = ((const float4*)src)[2];
    float4 f3 = ((const float4*)src)[3];
    float v[16];
    v[0] = f0.x; v[1] = f0.y; v[2] = f0.z; v[3] = f0.w;
    v[4] = f1.x; v[5] = f1.y; v[6] = f1.z; v[7] = f1.w;
    v[8] = f2.x; v[9] = f2.y; v[10] = f2.z; v[11] = f2.w;
    v[12] = f3.x; v[13] = f3.y; v[14] = f3.z; v[15] = f3.w;
#pragma unroll
    for (int j = 0; j < 8; j++) lt2[(d0 >> 1) + j][srow] = pk2(v[2 * j], v[2 * j + 1]);
    __syncthreads();
    const int dp = tid >> 3, soct = tid & 7;
    u32 a[8];
#pragma unroll
    for (int j = 0; j < 8; j++) a[j] = lt2[dp][soct * 8 + j];
    uint4 r0, r1;
    r0.x = (a[0] & 0xffffu) | (a[1] << 16);
    r0.y = (a[2] & 0xffffu) | (a[3] << 16);
    r0.z = (a[4] & 0xffffu) | (a[5] << 16);
    r0.w = (a[6] & 0xffffu) | (a[7] << 16);
    r1.x = (a[0] >> 16) | (a[1] & 0xffff0000u);
    r1.y = (a[2] >> 16) | (a[3] & 0xffff0000u);
    r1.z = (a[4] >> 16) | (a[5] & 0xffff0000u);
    r1.w = (a[6] >> 16) | (a[7] & 0xffff0000u);
    u16* dst0 = vt + ((size_t)(b * DD + dt * 64 + 2 * dp) * SS) + st * 64 + soct * 8;
    *(uint4*)dst0 = r0;
    *(uint4*)(dst0 + SS) = r1;
}

// ---------------- Kernel 3: fused attention, d-slice 256, fixed-M softmax, self-normalizing ----
__global__ __launch_bounds__(512, 4) void k_attn(const u16* __restrict__ qg, const u16* __restrict__ kg,
                                                 const u16* __restrict__ vt, float* __restrict__ out) {
    __shared__ __align__(16) u16 lq[128 * 64];   // 16KB, swizzled
    __shared__ __align__(16) u16 lk[64 * 64];    // 8KB, swizzled
    __shared__ __align__(16) u16 lv[256 * 64];   // 32KB, swizzled (row=d, col=k)
    __shared__ __align__(16) u16 lp[128 * 64];   // 16KB, swizzled (row=q, col=k)
    __shared__ float lsum[128];
    const int tid = threadIdx.x;
    const int w = tid >> 6, lane = tid & 63, l15 = lane & 15, quad = lane >> 4;
    const int ds = blockIdx.x, b = blockIdx.y, qt = 31 - blockIdx.z; // big tiles first; XCD=(ds+4b)%8
    const int q0 = qt * 128, d0 = ds * 256;
    const int kr = w & 1, qc = w >> 1;   // pass A: 2 k-slices x 4 q-slices
    const int dc = w & 3, qr = w >> 2;   // pass B: 4 d-slices x 2 q-halves
    const u16* qbase = qg + ((size_t)b * SS + q0) * EE;
    const u16* kbase = kg + (size_t)b * SS * EE;
    const u16* vbase = vt + ((size_t)b * DD + d0) * SS;

    if (tid < 128) lsum[tid] = 0.0f;
#pragma unroll
    for (int i = 0; i < 2; i++) {
        int goff = i * 512 + tid;
        int grow = goff >> 3, gp = goff & 7, glog = gp ^ (grow & 7);
        gload16(qbase + (size_t)grow * EE + glog * 8, (void*)&lq[goff * 8]);
    }
    __syncthreads();

    bf16x8 qf[2][2];
#pragma unroll
    for (int ct = 0; ct < 2; ct++) {
        int n = 32 * qc + 16 * ct + l15;
#pragma unroll
        for (int es = 0; es < 2; es++)
            qf[ct][es] = *(const bf16x8*)&lq[n * 64 + ((((es << 2) + quad) ^ (n & 7))) * 8];
    }
    f32x4 o[4][4];
#pragma unroll
    for (int i = 0; i < 4; i++)
#pragma unroll
        for (int j = 0; j < 4; j++) o[i][j] = f32x4{0.f, 0.f, 0.f, 0.f};
    float rl[2] = {0.f, 0.f};

    const int KT = 2 * qt + 2;
    for (int kt = 0; kt < KT; kt++) {
        const int k0 = kt * 64;
        __syncthreads();   // B0: prev pass B done with lk/lv/lp
        {
            int goff = tid;
            int grow = goff >> 3, gp = goff & 7, glog = gp ^ (grow & 7);
            gload16(kbase + (size_t)(k0 + grow) * EE + glog * 8, (void*)&lk[goff * 8]);
        }
#pragma unroll
        for (int i = 0; i < 4; i++) {
            int goff = i * 512 + tid;
            int grow = goff >> 3, gp = goff & 7, glog = gp ^ (grow & 7);
            gload16(vbase + (size_t)grow * SS + k0 + glog * 8, (void*)&lv[goff * 8]);
        }
        __syncthreads();   // B1: staging drained
        const bool diag = (k0 + 63 > q0);
#pragma unroll
        for (int rt = 0; rt < 2; rt++) {
            int mloc = 32 * kr + 16 * rt + l15;
            bf16x8 ka0 = *(const bf16x8*)&lk[mloc * 64 + ((quad ^ (mloc & 7))) * 8];
            bf16x8 ka1 = *(const bf16x8*)&lk[mloc * 64 + (((4 + quad) ^ (mloc & 7))) * 8];
#pragma unroll
            for (int ct = 0; ct < 2; ct++) {
                f32x4 c = f32x4{0.f, 0.f, 0.f, 0.f};
                c = MFMA(ka0, qf[ct][0], c);
                c = MFMA(ka1, qf[ct][1], c);
                int qv = 32 * qc + 16 * ct + l15;
                float p[4];
#pragma unroll
                for (int r = 0; r < 4; r++) {
                    float arg = __builtin_fmaf(c[r], SCALE2, -MFIX);
                    if (diag) {
                        int kpg = k0 + 32 * kr + 16 * rt + 4 * quad + r;
                        if (kpg > q0 + qv) arg = -3.0e38f;  // exp2 -> 0
                    }
                    p[r] = fexp2(arg);
                }
                rl[ct] += (p[0] + p[1]) + (p[2] + p[3]);
                int g16 = 4 * kr + 2 * rt + (quad >> 1);
                int phys = g16 ^ (qv & 7);
                uint2 pkk;
                pkk.x = pk2(p[0], p[1]);
                pkk.y = pk2(p[2], p[3]);
                *(uint2*)&lp[qv * 64 + phys * 8 + (quad & 1) * 4] = pkk;
            }
        }
        __syncthreads();   // B2: P ready
#pragma unroll
        for (int ks = 0; ks < 2; ks++) {
            bf16x8 vb[4];
#pragma unroll
            for (int ct = 0; ct < 4; ct++) {
                int n = 64 * dc + 16 * ct + l15;
                int phys = ((ks << 2) + quad) ^ (n & 7);
                vb[ct] = *(const bf16x8*)&lv[n * 64 + phys * 8];
            }
#pragma unroll
            for (int rt = 0; rt < 4; rt++) {
                int m = 64 * qr + 16 * rt + l15;
                int phys = ((ks << 2) + quad) ^ (m & 7);
                bf16x8 pa = *(const bf16x8*)&lp[m * 64 + phys * 8];
#pragma unroll
                for (int ct = 0; ct < 4; ct++) o[rt][ct] = MFMA(pa, vb[ct], o[rt][ct]);
            }
        }
    }
    // denominator: per-lane partials -> quad butterfly -> one atomic per row per kr-wave
#pragma unroll
    for (int ct = 0; ct < 2; ct++) {
        float t = rl[ct];
        t += __shfl_xor(t, 16, 64);
        t += __shfl_xor(t, 32, 64);
        if (quad == 0) atomicAdd(&lsum[32 * qc + 16 * ct + l15], t);
    }
    __syncthreads();
#pragma unroll
    for (int rt = 0; rt < 4; rt++) {
#pragma unroll
        for (int r = 0; r < 4; r++) {
            int row = 64 * qr + 16 * rt + 4 * quad + r;
            float li = 1.0f / lsum[row];
#pragma unroll
            for (int ct = 0; ct < 4; ct++) {
                int col = d0 + 64 * dc + 16 * ct + l15;
                out[((size_t)b * SS + q0 + row) * DD + col] = o[rt][ct][r] * li;
            }
        }
    }
}

extern "C" void kernel_launch(void* const* d_in, const int* in_sizes, int n_in,
                              void* d_out, int out_size, void* d_ws, size_t ws_size,
                              hipStream_t stream) {
    (void)in_sizes; (void)n_in; (void)out_size; (void)ws_size;
    const float* enc = (const float*)d_in[0];
    const float* wq = (const float*)d_in[1];
    const float* wk = (const float*)d_in[2];
    char* ws = (char*)d_ws;
    u16* qbf = (u16*)ws;                  // 2 MiB
    u16* kbf = (u16*)(ws + (2ull << 20)); // 2 MiB
    u16* vt  = (u16*)(ws + (4ull << 20)); // 32 MiB
    float* out = (float*)d_out;

    hipLaunchKernelGGL(k_proj, dim3(256), dim3(512), 0, stream, enc, wq, wk, qbf, kbf);
    hipLaunchKernelGGL(k_tcast, dim3(16, 64, 4), dim3(256), 0, stream, enc, vt);
    hipLaunchKernelGGL(k_attn, dim3(4, 4, 32), dim3(512), 0, stream, qbf, kbf, vt, out);
}